// Round 15
// baseline (154.222 us; speedup 1.0000x reference)
//
#include <hip/hip_runtime.h>

typedef __attribute__((ext_vector_type(4))) _Float16 f16x4;
typedef __attribute__((ext_vector_type(8))) _Float16 f16x8;
typedef __attribute__((ext_vector_type(4))) float f32x4;

#define NB 4096
#define TT 200
#define DD 64
#define H0 128
#define H1 64
#define BT 832   // 13 waves: one strip per wave

// ws layout (bytes)
#define WS_BC 0        // W0bcT fp16 [128][64] = 16384 B  (W0b - W0c, transposed)
#define WS_DD 16384    // W0dT  fp16 [128][64] = 16384 B  (W0d, transposed)
#define WS_W1 32768    // W1phi fp16 [64][128] = 16384 B  (phi-permuted, XOR-swizzled)
#define WS_CB 49152    // cb f32 [4096][128] = 2 MB

// ---- pre-kernel A: fold W0 -> fp16 transposed parts + phi-permuted W1 image ----
// phi(g4,jj) = 4*g4 + (jj&3) + 16*(jj>>2): the k-labeling that matches the
// layer0 D-fragment layout, so layer1's A-frag is ONE b128 per (c1,m).
// W1 image XOR-swizzled on 16B units: unit ^= (row & 15) -> conflict-free b128.
__global__ __launch_bounds__(256)
void pre_fold(const float* __restrict__ W0, const float* __restrict__ W1,
              unsigned char* __restrict__ ws)
{
  int idx = blockIdx.x * 256 + threadIdx.x;   // grid 64 -> 16384 threads
  _Float16* bcT  = (_Float16*)(ws + WS_BC);
  _Float16* ddT  = (_Float16*)(ws + WS_DD);
  _Float16* w1p  = (_Float16*)(ws + WS_W1);
  if (idx < 8192) {
    int h = idx >> 6, d = idx & 63;
    bcT[h * 64 + d] = (_Float16)(W0[(64 + d) * H0 + h] - W0[(128 + d) * H0 + h]);
    ddT[h * 64 + d] = (_Float16)(W0[(192 + d) * H0 + h]);
  } else {
    int i = idx - 8192;                       // 0..8191
    int jrow = i >> 7, p = i & 127;           // p = m*32 + g4p*8 + jj
    int m = p >> 5, g4p = (p >> 3) & 3, jj = p & 7;
    int h = 32 * m + 16 * (jj >> 2) + 4 * g4p + (jj & 3);
    int up = p >> 3, wi = p & 7;              // 16B unit, half-within-unit
    w1p[jrow * 128 + (((up ^ (jrow & 15)) << 3) | wi)] = (_Float16)W1[h * H1 + jrow];
  }
}

// ---- pre-kernel B: cb[b][h] = b0[h] + q[b] @ (W0a + W0c) ----
__global__ __launch_bounds__(256)
void pre_cb(const float* __restrict__ q, const float* __restrict__ W0,
            const float* __restrict__ b0, unsigned char* __restrict__ ws)
{
  __shared__ float WacS[DD * H0];   // 32 KB, [d][h]
  __shared__ float qS2[2][DD];
  const int tid = threadIdx.x;
  float* cb = (float*)(ws + WS_CB);

  #pragma unroll 4
  for (int i = 0; i < 32; ++i) {
    int idx = i * 256 + tid;
    int d = idx >> 7, h = idx & 127;
    WacS[idx] = W0[d * H0 + h] + W0[(128 + d) * H0 + h];
  }
  __syncthreads();

  const int half = tid >> 7, h = tid & 127;
  #pragma unroll 1
  for (int p = 0; p < 16; ++p) {
    int bpair = blockIdx.x * 32 + p * 2;      // grid 128
    if (tid < DD) qS2[0][tid] = q[(size_t)bpair * DD + tid];
    else if (tid >= 128 && tid < 128 + DD) qS2[1][tid - 128] = q[(size_t)(bpair + 1) * DD + (tid - 128)];
    __syncthreads();
    float s = b0[h];
    #pragma unroll 8
    for (int d = 0; d < DD; ++d) s = fmaf(qS2[half][d], WacS[d * H0 + h], s);
    cb[(size_t)(bpair + half) * H0 + h] = s;
    __syncthreads();
  }
}

// ---- main kernel ----
// Transposed-GEMM DIN attention, fp16 weights/acts, fp32 accum/softmax, both
// layers on mfma_f32_16x16x32_f16 (k-relabeling: layer1 uses phi = D-frag
// layout; exact since k is contracted and A/B lane->k maps are identical).
// R15: 13-wave (832-thread) blocks, ONE strip per wave -- removes the 4-deep
// serial strip loop that dominated per-block latency (R12-R14: all pipes <26%,
// ~23us/block vs ~6us modeled work). 2 blocks/CU (thread-limited) = 26 wave
// slots; (832,6) caps regs at 85 total (natural demand ~84: 60 arch + 24 acc,
// R7-R14 evidence) -> 6 waves/SIMD. Pool/softmax per-wave over own 16 t's.
// Codegen rules (R2-R14): inner loops fully unrolled + static reg indexing,
// m-loop unroll 1, 16B-unit XOR swizzles (bank-conflict 0 in R14).
__global__ __launch_bounds__(BT, 6)
void din_attn(const float* __restrict__ q, const float* __restrict__ k,
              const float* __restrict__ v, const int* __restrict__ mask,
              const float* __restrict__ b1, const float* __restrict__ Wf,
              const unsigned char* __restrict__ ws, float* __restrict__ out)
{
  const int b    = blockIdx.x;
  const int tid  = threadIdx.x;
  const int lane = tid & 63;
  const int wid  = tid >> 6;     // 0..12 == strip id
  const int r16  = lane & 15;
  const int g4   = lane >> 4;

  __shared__ __align__(16) _Float16 MhT[H0 * 64];   // 16384 B, XOR 16B units
  __shared__ __align__(16) _Float16 W1p[H1 * 128];  // 16384 B, XOR 16B units
  __shared__ __align__(16) float qS[DD];
  __shared__ __align__(16) float cbS[H0];
  __shared__ __align__(16) float b1S[H1];
  __shared__ __align__(16) float WfS[H1];
  __shared__ float sP[208];
  __shared__ float red[32];          // [0..12] max, [16..28] sum
  __shared__ float pool[13 * 64];

  const float* qb = q + b * DD;
  const float* kb = k + (size_t)b * TT * DD;
  const float* vb = v + (size_t)b * TT * DD;
  const int*   mb = mask + b * TT;

  // ---- staging (before barrier 1) ----
  {
    const uint4* src = (const uint4*)(ws + WS_W1);
    uint4* dst = (uint4*)W1p;
    dst[tid < 1024 ? tid : 0] = src[tid < 1024 ? tid : 0];  // tid<832 all valid
    if (tid < 192) dst[832 + tid] = src[832 + tid];
  }
  if (tid < DD) qS[tid] = qb[tid];
  else if (tid >= 64 && tid < 64 + H0)
    cbS[tid - 64] = ((const float*)(ws + WS_CB))[(size_t)b * H0 + (tid - 64)];
  else if (tid >= 192 && tid < 192 + H1) b1S[tid - 192] = b1[tid - 192];
  else if (tid >= 256 && tid < 256 + H1) WfS[tid - 256] = Wf[tid - 256];

  // own strip's k + mask issued before barrier (no LDS dependence)
  const int dof = 8 * g4;
  const int t0   = wid * 16;
  const int trow = t0 + r16;
  const int tck  = trow < TT ? trow : TT - 1;   // clamp; masked below anyway
  float4 kq0 = *(const float4*)(kb + tck * DD + dof);
  float4 kq1 = *(const float4*)(kb + tck * DD + dof + 4);
  float4 kq2 = *(const float4*)(kb + tck * DD + 32 + dof);
  float4 kq3 = *(const float4*)(kb + tck * DD + 32 + dof + 4);
  const int mm = (trow < TT) ? mb[trow] : -1;
  __syncthreads();   // qS ready

  // M_b build: 1024 slots, slot = (h = idx>>3, unit u = idx&7)
  #pragma unroll 1
  for (int idx = tid; idx < 1024; idx += BT) {
    const _Float16* bcT = (const _Float16*)(ws + WS_BC);
    const _Float16* ddT = (const _Float16*)(ws + WS_DD);
    const int u = idx & 7, h = idx >> 3;
    const int dblk = u * 8;
    f16x8 bc8 = *(const f16x8*)(bcT + h * 64 + dblk);
    f16x8 dd8 = *(const f16x8*)(ddT + h * 64 + dblk);
    f16x8 o8;
    #pragma unroll
    for (int j = 0; j < 8; ++j)
      o8[j] = (_Float16)((float)bc8[j] + qS[dblk + j] * (float)dd8[j]);
    *(f16x8*)(&MhT[h * 64 + ((u ^ (h & 7)) << 3)]) = o8;
  }
  __syncthreads();

  const int k8 = r16 & 7;   // MhT swizzle key
  const int kW = r16;       // W1p swizzle key

  // ---- pass 1: ONE strip per wave ----
  {
    f16x8 bh0, bh1;
    {
      float f0[8] = {kq0.x, kq0.y, kq0.z, kq0.w, kq1.x, kq1.y, kq1.z, kq1.w};
      float f1[8] = {kq2.x, kq2.y, kq2.z, kq2.w, kq3.x, kq3.y, kq3.z, kq3.w};
      #pragma unroll
      for (int j = 0; j < 8; ++j) {
        bh0[j] = (_Float16)f0[j];
        bh1[j] = (_Float16)f1[j];
      }
    }

    f32x4 acc1[4];
    #pragma unroll
    for (int c1 = 0; c1 < 4; ++c1) acc1[c1] = (f32x4){0.f, 0.f, 0.f, 0.f};

    #pragma unroll 1
    for (int m = 0; m < 4; ++m) {
      const _Float16* rowE = &MhT[((2 * m) * 16 + r16) * 64];
      const _Float16* rowO = rowE + 16 * 64;
      f16x8 afE0 = *(const f16x8*)(rowE + ((g4 ^ k8) << 3));
      f16x8 afE1 = *(const f16x8*)(rowE + (((g4 + 4) ^ k8) << 3));
      f32x4 a0e = {0.f, 0.f, 0.f, 0.f};
      a0e = __builtin_amdgcn_mfma_f32_16x16x32_f16(afE0, bh0, a0e, 0, 0, 0);
      a0e = __builtin_amdgcn_mfma_f32_16x16x32_f16(afE1, bh1, a0e, 0, 0, 0);
      f16x8 afO0 = *(const f16x8*)(rowO + ((g4 ^ k8) << 3));
      f16x8 afO1 = *(const f16x8*)(rowO + (((g4 + 4) ^ k8) << 3));
      f32x4 a0o = {0.f, 0.f, 0.f, 0.f};
      a0o = __builtin_amdgcn_mfma_f32_16x16x32_f16(afO0, bh0, a0o, 0, 0, 0);
      a0o = __builtin_amdgcn_mfma_f32_16x16x32_f16(afO1, bh1, a0o, 0, 0, 0);

      f32x4 cbe = *(const f32x4*)(&cbS[(2 * m) * 16 + 4 * g4]);
      f32x4 cbo = *(const f32x4*)(&cbS[(2 * m) * 16 + 16 + 4 * g4]);
      f16x8 hf;
      #pragma unroll
      for (int r = 0; r < 4; ++r) {
        float he = a0e[r] + cbe[r];
        float ho = a0o[r] + cbo[r];
        hf[r]     = (_Float16)(he > 0.f ? he : 0.f);
        hf[4 + r] = (_Float16)(ho > 0.f ? ho : 0.f);
      }
      #pragma unroll
      for (int c1 = 0; c1 < 4; ++c1) {
        f16x8 af1 = *(const f16x8*)(&W1p[(c1 * 16 + r16) * 128
                                         + (((4 * m + g4) ^ kW) << 3)]);
        acc1[c1] = __builtin_amdgcn_mfma_f32_16x16x32_f16(af1, hf, acc1[c1], 0, 0, 0);
      }
    }

    float p = 0.f;
    #pragma unroll
    for (int c1 = 0; c1 < 4; ++c1) {
      f32x4 b14 = *(const f32x4*)(&b1S[c1 * 16 + 4 * g4]);
      f32x4 wf4 = *(const f32x4*)(&WfS[c1 * 16 + 4 * g4]);
      #pragma unroll
      for (int r = 0; r < 4; ++r) {
        float h1 = acc1[c1][r] + b14[r];
        h1 = h1 > 0.f ? h1 : 0.f;
        p = fmaf(h1, wf4[r], p);
      }
    }
    p += __shfl_xor(p, 16, 64);
    p += __shfl_xor(p, 32, 64);
    p = (mm == 1) ? p : (mm == 0 ? -1e30f : -2e30f);
    if (g4 == 0) sP[t0 + r16] = p;
  }
  __syncthreads();

  // ---- v loads early: each wave pools its own strip's 16 t's ----
  const int tg = lane >> 4;
  const int dq = lane & 15;
  f32x4 vv0, vv1, vv2, vv3;
  {
    int ta = t0 + 4 * 0 + tg, tb = t0 + 4 * 1 + tg;
    int tc2 = t0 + 4 * 2 + tg, td = t0 + 4 * 3 + tg;
    vv0 = *(const f32x4*)(vb + (ta < TT ? ta : TT - 1) * DD + dq * 4);
    vv1 = *(const f32x4*)(vb + (tb < TT ? tb : TT - 1) * DD + dq * 4);
    vv2 = *(const f32x4*)(vb + (tc2 < TT ? tc2 : TT - 1) * DD + dq * 4);
    vv3 = *(const f32x4*)(vb + (td < TT ? td : TT - 1) * DD + dq * 4);
  }

  // ---- pass 2: exact softmax over sP[0..207] (waves 4+ carry neutral vals) ----
  float rcpS;
  {
    float val = (tid < 208) ? sP[tid] : -3e30f;
    float mx = val;
    #pragma unroll
    for (int off = 32; off >= 1; off >>= 1) mx = fmaxf(mx, __shfl_xor(mx, off, 64));
    if (lane == 0) red[wid] = mx;
    __syncthreads();
    float M = red[0];
    #pragma unroll
    for (int w = 1; w < 13; ++w) M = fmaxf(M, red[w]);
    float e = (tid < 208) ? __expf(val - M) : 0.f;
    float se = e;
    #pragma unroll
    for (int off = 32; off >= 1; off >>= 1) se += __shfl_xor(se, off, 64);
    if (lane == 0) red[16 + wid] = se;
    __syncthreads();
    float S = 0.f;
    #pragma unroll
    for (int w = 0; w < 13; ++w) S += red[16 + w];
    rcpS = 1.f / S;
    if (tid < 208) sP[tid] = e;
  }
  __syncthreads();

  // ---- pass 3: pool own strip (sP[t>=200] == 0 via mask) ----
  {
    f32x4 o4 = {0.f, 0.f, 0.f, 0.f};
    float w0 = sP[t0 + 4 * 0 + tg];
    float w1 = sP[t0 + 4 * 1 + tg];
    float w2 = sP[t0 + 4 * 2 + tg];
    float w3 = sP[t0 + 4 * 3 + tg];
    #pragma unroll
    for (int j = 0; j < 4; ++j)
      o4[j] = fmaf(w0, vv0[j], fmaf(w1, vv1[j], fmaf(w2, vv2[j], w3 * vv3[j])));
    #pragma unroll
    for (int j = 0; j < 4; ++j) {
      o4[j] += __shfl_xor(o4[j], 16, 64);
      o4[j] += __shfl_xor(o4[j], 32, 64);
    }
    if (tg == 0) *(f32x4*)(&pool[wid * 64 + dq * 4]) = o4;
  }
  __syncthreads();

  if (tid < DD) {
    float acc = 0.f;
    #pragma unroll
    for (int w = 0; w < 13; ++w) acc += pool[w * 64 + tid];
    out[b * DD + tid] = acc * rcpS;
  }
}

extern "C" void kernel_launch(void* const* d_in, const int* in_sizes, int n_in,
                              void* d_out, int out_size, void* d_ws, size_t ws_size,
                              hipStream_t stream) {
  const float* q    = (const float*)d_in[0];
  const float* k    = (const float*)d_in[1];
  const float* v    = (const float*)d_in[2];
  const int*   mask = (const int*)d_in[3];
  const float* W0   = (const float*)d_in[4];
  const float* b0   = (const float*)d_in[5];
  const float* W1   = (const float*)d_in[6];
  const float* b1   = (const float*)d_in[7];
  const float* Wf   = (const float*)d_in[8];
  float* out = (float*)d_out;
  unsigned char* ws = (unsigned char*)d_ws;

  pre_fold<<<dim3(64), dim3(256), 0, stream>>>(W0, W1, ws);
  pre_cb<<<dim3(128), dim3(256), 0, stream>>>(q, W0, b0, ws);
  din_attn<<<dim3(NB), dim3(BT), 0, stream>>>(q, k, v, mask, b1, Wf, ws, out);
}